// Round 1
// baseline (720.354 us; speedup 1.0000x reference)
//
#include <hip/hip_runtime.h>
#include <math.h>

// Problem constants (from reference): B=2048 rows, C=32000 cols, fp32.
constexpr int BROWS = 2048;
constexpr int C     = 32000;
constexpr int C4    = C / 4;          // 8000 float4 per row
constexpr int NT    = 1024;           // threads per block (16 waves)
constexpr int NW    = NT / 64;        // 16 waves
constexpr int PER   = (C4 + NT - 1) / NT;  // 8 float4 per thread (last partial)

__global__ __launch_bounds__(NT, 4) void fused_fill_softmax_kernel(
    const float* __restrict__ x,
    const float* __restrict__ u,
    const float* __restrict__ nz,
    float* __restrict__ out)
{
    __shared__ float s_vals[NW];
    __shared__ int   s_idxs[NW];
    __shared__ float s_m;
    __shared__ int   s_amax;
    __shared__ float s_mx;
    __shared__ float s_sum;

    const int row  = blockIdx.x;
    const int tid  = threadIdx.x;
    const int lane = tid & 63;
    const int wid  = tid >> 6;

    const size_t roff = (size_t)row * C;
    const float4* x4 = (const float4*)(x  + roff);
    const float4* u4 = (const float4*)(u  + roff);
    const float4* n4 = (const float4*)(nz + roff);
    float4*       o4 = (float4*)(out + roff);

    // ---------- Phase A: row max + argmax of x (first occurrence) ----------
    float bm = -INFINITY;
    int   bi = 0x7fffffff;
#pragma unroll
    for (int k = 0; k < PER; ++k) {
        int i = tid + k * NT;
        if (i < C4) {
            float4 v = x4[i];
            int base = i * 4;
            // strict > + in-order scan => lowest index wins within thread
            if (v.x > bm) { bm = v.x; bi = base;     }
            if (v.y > bm) { bm = v.y; bi = base + 1; }
            if (v.z > bm) { bm = v.z; bi = base + 2; }
            if (v.w > bm) { bm = v.w; bi = base + 3; }
        }
    }
#pragma unroll
    for (int off = 32; off > 0; off >>= 1) {
        float om = __shfl_down(bm, off, 64);
        int   oi = __shfl_down(bi, off, 64);
        if (om > bm || (om == bm && oi < bi)) { bm = om; bi = oi; }
    }
    if (lane == 0) { s_vals[wid] = bm; s_idxs[wid] = bi; }
    __syncthreads();
    if (wid == 0) {
        bm = (lane < NW) ? s_vals[lane] : -INFINITY;
        bi = (lane < NW) ? s_idxs[lane] : 0x7fffffff;
#pragma unroll
        for (int off = 8; off > 0; off >>= 1) {
            float om = __shfl_down(bm, off, 64);
            int   oi = __shfl_down(bi, off, 64);
            if (om > bm || (om == bm && oi < bi)) { bm = om; bi = oi; }
        }
        if (lane == 0) { s_m = bm; s_amax = bi; }
    }
    __syncthreads();
    const float m    = s_m;
    const int   amax = s_amax;

    // ---------- Phase B: x2 = where(j==amax, m, (0.1+0.2u)*m) + noise ----------
    float4 r[PER];
    float lmax = -INFINITY;
#pragma unroll
    for (int k = 0; k < PER; ++k) {
        int i = tid + k * NT;
        if (i < C4) {
            float4 uu = u4[i];
            float4 nn = n4[i];
            int base = i * 4;
            float4 v;
            v.x = ((base + 0 == amax) ? m : (0.1f + 0.2f * uu.x) * m) + nn.x;
            v.y = ((base + 1 == amax) ? m : (0.1f + 0.2f * uu.y) * m) + nn.y;
            v.z = ((base + 2 == amax) ? m : (0.1f + 0.2f * uu.z) * m) + nn.z;
            v.w = ((base + 3 == amax) ? m : (0.1f + 0.2f * uu.w) * m) + nn.w;
            r[k] = v;
            lmax = fmaxf(lmax, fmaxf(fmaxf(v.x, v.y), fmaxf(v.z, v.w)));
        }
    }
#pragma unroll
    for (int off = 32; off > 0; off >>= 1)
        lmax = fmaxf(lmax, __shfl_down(lmax, off, 64));
    if (lane == 0) s_vals[wid] = lmax;
    __syncthreads();
    if (wid == 0) {
        lmax = (lane < NW) ? s_vals[lane] : -INFINITY;
#pragma unroll
        for (int off = 8; off > 0; off >>= 1)
            lmax = fmaxf(lmax, __shfl_down(lmax, off, 64));
        if (lane == 0) s_mx = lmax;
    }
    __syncthreads();
    const float mx = s_mx;

    // ---------- Phase C: exp + sum ----------
    float lsum = 0.f;
#pragma unroll
    for (int k = 0; k < PER; ++k) {
        int i = tid + k * NT;
        if (i < C4) {
            float4 v = r[k];
            v.x = __expf(v.x - mx);
            v.y = __expf(v.y - mx);
            v.z = __expf(v.z - mx);
            v.w = __expf(v.w - mx);
            r[k] = v;
            lsum += (v.x + v.y) + (v.z + v.w);
        }
    }
#pragma unroll
    for (int off = 32; off > 0; off >>= 1)
        lsum += __shfl_down(lsum, off, 64);
    if (lane == 0) s_vals[wid] = lsum;
    __syncthreads();
    if (wid == 0) {
        lsum = (lane < NW) ? s_vals[lane] : 0.f;
#pragma unroll
        for (int off = 8; off > 0; off >>= 1)
            lsum += __shfl_down(lsum, off, 64);
        if (lane == 0) s_sum = lsum;
    }
    __syncthreads();
    const float inv = 1.0f / s_sum;

    // ---------- Phase D: scale + coalesced store ----------
#pragma unroll
    for (int k = 0; k < PER; ++k) {
        int i = tid + k * NT;
        if (i < C4) {
            float4 v = r[k];
            v.x *= inv; v.y *= inv; v.z *= inv; v.w *= inv;
            o4[i] = v;
        }
    }
}

extern "C" void kernel_launch(void* const* d_in, const int* in_sizes, int n_in,
                              void* d_out, int out_size, void* d_ws, size_t ws_size,
                              hipStream_t stream) {
    const float* x  = (const float*)d_in[0];
    const float* u  = (const float*)d_in[1];
    const float* nz = (const float*)d_in[2];
    float* out = (float*)d_out;
    fused_fill_softmax_kernel<<<BROWS, NT, 0, stream>>>(x, u, nz, out);
}